// Round 6
// baseline (334.239 us; speedup 1.0000x reference)
//
#include <hip/hip_runtime.h>
#include <hip/hip_bf16.h>

// Problem constants
#define BB   2
#define LL   2048
#define DD   2048
#define HH   16
#define KVH  4
#define HDD  128
#define RDD  64
#define MM   (BB*LL)   // 4096 rows of x

typedef __attribute__((ext_vector_type(4))) float f32x4;
typedef __attribute__((ext_vector_type(8))) short bf16x8;
typedef unsigned short u16;

static __device__ __forceinline__ u16 f2b(float f) {
  __hip_bfloat16 b = __float2bfloat16(f);
  return *(const u16*)&b;
}

// async global(16B/lane) -> LDS (wave-uniform base + lane*16)
static __device__ __forceinline__ void gload_lds16(const void* g, void* l) {
  __builtin_amdgcn_global_load_lds(
      (const __attribute__((address_space(1))) unsigned int*)g,
      (__attribute__((address_space(3))) unsigned int*)l, 16, 0, 0);
}

// ---------------- f32 -> bf16 cast (vectorized) ----------------
__global__ __launch_bounds__(256) void cast_bf16_kernel(const float* __restrict__ in,
                                                        u16* __restrict__ out, int n4) {
  int i = blockIdx.x * 256 + threadIdx.x;
  if (i >= n4) return;
  float4 v = ((const float4*)in)[i];
  ushort4 o;
  o.x = f2b(v.x); o.y = f2b(v.y); o.z = f2b(v.z); o.w = f2b(v.w);
  ((ushort4*)out)[i] = o;
}

// ---------------- small GEMM (kept for N=64): C[M,N] = A @ W^T + bias ----------------
__global__ __launch_bounds__(64) void gemm_bf16_nt(const u16* __restrict__ A,
                                                   const u16* __restrict__ W,
                                                   const float* __restrict__ bias,
                                                   float* __restrict__ C,
                                                   int M, int N, int K) {
  const int n0 = blockIdx.x * 16;
  const int m0 = blockIdx.y * 16;
  const int lane = threadIdx.x;
  const int r  = lane & 15;
  const int kq = (lane >> 4) * 8;
  const u16* ap = A + (size_t)(m0 + r) * K + kq;
  const u16* wp = W + (size_t)(n0 + r) * K + kq;
  f32x4 acc = {0.f, 0.f, 0.f, 0.f};
  for (int k = 0; k < K; k += 32) {
    bf16x8 a = *(const bf16x8*)(ap + k);
    bf16x8 b = *(const bf16x8*)(wp + k);
    acc = __builtin_amdgcn_mfma_f32_16x16x32_bf16(a, b, acc, 0, 0, 0);
  }
  const int col = lane & 15;
  const int rg  = (lane >> 4) * 4;
  const float bv = bias[n0 + col];
#pragma unroll
  for (int i = 0; i < 4; ++i)
    C[(size_t)(m0 + rg + i) * N + (n0 + col)] = acc[i] + bv;
}

// ---------------- m97-style 128x128 tile GEMM ----
__global__ __launch_bounds__(256) void gemm128(const u16* __restrict__ A,
                                               const u16* __restrict__ W,
                                               const float* __restrict__ bias,
                                               float* __restrict__ C,
                                               int M, int N, int K) {
  __shared__ u16 As[128 * 32];
  __shared__ u16 Bs[128 * 32];
  const int w = threadIdx.x >> 6, lane = threadIdx.x & 63;
  const int r = lane & 15, hi = lane >> 4, rg = hi * 4;
  const int wm = w >> 1, wn = w & 1;
  const int m0 = blockIdx.y * 128, n0 = blockIdx.x * 128;
  const int srow = w * 32 + (lane >> 2);
  const int scb  = (lane & 3) * 16;
  f32x4 acc[4][4];
#pragma unroll
  for (int i = 0; i < 4; ++i)
#pragma unroll
    for (int j = 0; j < 4; ++j) acc[i][j] = (f32x4){0.f, 0.f, 0.f, 0.f};

  for (int k0 = 0; k0 < K; k0 += 32) {
#pragma unroll
    for (int i = 0; i < 2; ++i) {
      gload_lds16((const char*)(A + (size_t)(m0 + srow + i * 16) * K + k0) + scb,
                  (char*)As + (w * 2 + i) * 1024);
      gload_lds16((const char*)(W + (size_t)(n0 + srow + i * 16) * K + k0) + scb,
                  (char*)Bs + (w * 2 + i) * 1024);
    }
    __syncthreads();
    bf16x8 a[4], b[4];
#pragma unroll
    for (int i = 0; i < 4; ++i)
      a[i] = *(const bf16x8*)((const char*)As + (wm * 64 + i * 16 + r) * 64 + hi * 16);
#pragma unroll
    for (int j = 0; j < 4; ++j)
      b[j] = *(const bf16x8*)((const char*)Bs + (wn * 64 + j * 16 + r) * 64 + hi * 16);
#pragma unroll
    for (int i = 0; i < 4; ++i)
#pragma unroll
      for (int j = 0; j < 4; ++j)
        acc[i][j] = __builtin_amdgcn_mfma_f32_16x16x32_bf16(a[i], b[j], acc[i][j], 0, 0, 0);
    __syncthreads();
  }
#pragma unroll
  for (int j = 0; j < 4; ++j) {
    const float bv = bias[n0 + wn * 64 + j * 16 + r];
#pragma unroll
    for (int i = 0; i < 4; ++i)
#pragma unroll
      for (int ii = 0; ii < 4; ++ii)
        C[(size_t)(m0 + wm * 64 + i * 16 + rg + ii) * N + n0 + wn * 64 + j * 16 + r] =
            acc[i][j][ii] + bv;
  }
}

// ---------------- build Qb: rope + scale + bf16, head-major [b][h][l][128] ----------------
__global__ __launch_bounds__(256) void build_q_kernel(const float* __restrict__ qbuf,
                                                      const float* __restrict__ cosb,
                                                      const float* __restrict__ sinb,
                                                      u16* __restrict__ Qb) {
  const int idx = blockIdx.x * 256 + threadIdx.x;
  const int d = idx & 127;
  const int t = idx >> 7;
  const int l = t & 2047;
  const int bh = t >> 11;
  const int h = bh & 15, b = bh >> 4;
  const int n = b * LL + l;
  const float qscale = 0.08838834764831845f;
  const float* qp = qbuf + (size_t)n * DD + h * HDD;
  float val;
  if (d < 64) {
    val = qp[d];
  } else {
    const int i = d - 64;
    const float cv = cosb[(size_t)n * RDD + i];
    const float sv = sinb[(size_t)n * RDD + i];
    val = (i < 32) ? (qp[d] * cv - qp[d + 32] * sv)
                   : (qp[d] * cv + qp[d - 32] * sv);
  }
  Qb[idx] = f2b(val * qscale);
}

// ---------------- build Kb: [kv_tied | roped k_rope] bf16, [b][c][s][128] ----------------
__global__ __launch_bounds__(256) void build_k_kernel(const float* __restrict__ kvbuf,
                                                      const float* __restrict__ krbuf,
                                                      const float* __restrict__ cosb,
                                                      const float* __restrict__ sinb,
                                                      u16* __restrict__ Kb) {
  const int idx = blockIdx.x * 256 + threadIdx.x;
  const int d = idx & 127;
  const int t = idx >> 7;
  const int s = t & 2047;
  const int bc = t >> 11;
  const int b = bc >> 2, c = bc & 3;
  const int n = b * LL + s;
  float val;
  if (d < 64) {
    val = kvbuf[(size_t)n * (KVH * HDD) + c * HDD + d];
  } else {
    const int i = d - 64;
    const float cv = cosb[(size_t)n * RDD + i];
    const float sv = sinb[(size_t)n * RDD + i];
    const float* kr = krbuf + (size_t)n * RDD;
    val = (i < 32) ? (kr[i] * cv - kr[i + 32] * sv)
                   : (kr[i] * cv + kr[i - 32] * sv);
  }
  Kb[idx] = f2b(val);
}

// ---------------- build VT: transpose V to [b][c][d][s] bf16 ----------------
__global__ __launch_bounds__(256) void build_vt_kernel(const float* __restrict__ kvbuf,
                                                       u16* __restrict__ VT) {
  __shared__ float tile[32][33];
  const int bc = blockIdx.z;
  const int b = bc >> 2, c = bc & 3;
  const int s0 = blockIdx.x * 32, d0 = blockIdx.y * 32;
  const int tx = threadIdx.x & 31, ty = threadIdx.x >> 5;
#pragma unroll
  for (int k = 0; k < 4; ++k) {
    const int s = s0 + ty + k * 8;
    tile[ty + k * 8][tx] = kvbuf[(size_t)(b * LL + s) * (KVH * HDD) + c * HDD + d0 + tx];
  }
  __syncthreads();
#pragma unroll
  for (int k = 0; k < 4; ++k) {
    const int d = d0 + ty + k * 8;
    VT[(size_t)(bc * HDD + d) * LL + s0 + tx] = f2b(tile[tx][ty + k * 8]);
  }
}

// ---------------- stage one KV tile (KVB=64) into LDS, slot-linear subtiled ----------------
// K LDS layout:  off(row,ks,hi) = (row>>4)*4096 + ks*1024 + (row&15)*64 + hi*16   (16KB)
// VT LDS layout: off(d,kb,hi)   = (d>>4)*2048  + kb*1024 + (d&15)*64  + hi*16    (16KB)
// global_load_lds writes linearly (dest j*1024 + lane*16), so the layout is realized
// by permuting the per-lane GLOBAL source address (m173 pattern).
static __device__ __forceinline__ void stage64(const char* Kg, const char* Vg,
                                               u16* kbuf, u16* vbuf,
                                               int s0, int w, int lane) {
#pragma unroll
  for (int i = 0; i < 4; ++i) {
    const int j = w * 4 + i;                          // 0..15
    const int krow = (j >> 2) * 16 + (lane >> 2);     // rowgrp*16 + (row&15)
    gload_lds16(Kg + (size_t)(s0 + krow) * 256 + (j & 3) * 64 + (lane & 3) * 16,
                (char*)kbuf + j * 1024);
    const int vd = (j >> 1) * 16 + (lane >> 2);       // dgrp*16 + (d&15)
    gload_lds16(Vg + (size_t)vd * (LL * 2) + (size_t)s0 * 2 + (j & 1) * 64 + (lane & 3) * 16,
                (char*)vbuf + j * 1024);
  }
}

// ---------------- MFMA flash attention v4: KVB=64, conflict-free LDS ----------------
// grid 512 blocks; 4 waves x 32 q-rows; S^T = mfma(K,Q) -> in-lane softmax.
__global__ __launch_bounds__(256, 1) void attn_mfma4(const u16* __restrict__ Qb,
                                                     const u16* __restrict__ Kb,
                                                     const u16* __restrict__ VTb,
                                                     u16* __restrict__ attn_bf) {
  const int id = blockIdx.x;
  const int bh = id & 31;
  const int strip = id >> 5;
  const int qb = (strip < 8) ? (15 - strip) : (strip - 8);
  const int b = bh >> 4, h = bh & 15, c = h >> 2;
  const int w = threadIdx.x >> 6, lane = threadIdx.x & 63;
  const int r = lane & 15, hi = lane >> 4, rg = hi * 4;
  const int q0 = qb * 128 + w * 32;

  __shared__ u16 Ks[2][8192];                    // 16KB x2
  __shared__ u16 Vs[2][8192];                    // 16KB x2
  __shared__ __align__(16) u16 Ps[4][2048];      // per-wave P: [qs][kb][r][slot][j] 4KB

  const u16* Qp = Qb + (size_t)bh * LL * HDD;
  const char* Kg = (const char*)(Kb + (size_t)(b * KVH + c) * LL * HDD);
  const char* Vg = (const char*)(VTb + (size_t)(b * KVH + c) * HDD * LL);

  bf16x8 qf[2][4];
#pragma unroll
  for (int qs = 0; qs < 2; ++qs)
#pragma unroll
    for (int ks = 0; ks < 4; ++ks)
      qf[qs][ks] = *(const bf16x8*)(Qp + (size_t)(q0 + qs * 16 + r) * HDD + ks * 32 + hi * 8);

  float m_[2] = {-3.0e38f, -3.0e38f}, l_[2] = {0.f, 0.f};
  f32x4 o[2][8];
#pragma unroll
  for (int qs = 0; qs < 2; ++qs)
#pragma unroll
    for (int t = 0; t < 8; ++t) o[qs][t] = (f32x4){0.f, 0.f, 0.f, 0.f};

  const int nt = 2 * qb + 2;                     // 64-key tiles

  stage64(Kg, Vg, Ks[0], Vs[0], 0, w, lane);
  __syncthreads();
  int cur = 0;

  for (int t = 0; t < nt; ++t) {
    const int s0 = t * 64;
    if (t + 1 < nt)
      stage64(Kg, Vg, Ks[cur ^ 1], Vs[cur ^ 1], s0 + 64, w, lane);

    const char* Kl = (const char*)Ks[cur];
    const char* Vl = (const char*)Vs[cur];

    // ---- swapped QK^T: st[qs][tt]: query col = r, key rows = tt*16 + rg + i ----
    f32x4 st[2][4];
#pragma unroll
    for (int qs = 0; qs < 2; ++qs)
#pragma unroll
      for (int tt = 0; tt < 4; ++tt) st[qs][tt] = (f32x4){0.f, 0.f, 0.f, 0.f};
    __builtin_amdgcn_s_setprio(1);
#pragma unroll
    for (int tt = 0; tt < 4; ++tt) {
      bf16x8 kf[4];
#pragma unroll
      for (int ks = 0; ks < 4; ++ks)
        kf[ks] = *(const bf16x8*)(Kl + tt * 4096 + ks * 1024 + r * 64 + hi * 16);
#pragma unroll
      for (int qs = 0; qs < 2; ++qs)
#pragma unroll
        for (int ks = 0; ks < 4; ++ks)
          st[qs][tt] = __builtin_amdgcn_mfma_f32_16x16x32_bf16(kf[ks], qf[qs][ks], st[qs][tt], 0, 0, 0);
    }
    __builtin_amdgcn_s_setprio(0);

    // ---- causal mask ----
    if (s0 + 63 > q0) {
#pragma unroll
      for (int qs = 0; qs < 2; ++qs)
#pragma unroll
        for (int tt = 0; tt < 4; ++tt)
#pragma unroll
          for (int i = 0; i < 4; ++i)
            if (s0 + tt * 16 + rg + i > q0 + qs * 16 + r) st[qs][tt][i] = -3.0e38f;
    }

    // ---- in-lane max + 2 shuffles ----
    float vmax[2];
#pragma unroll
    for (int qs = 0; qs < 2; ++qs) {
      float v = st[qs][0][0];
#pragma unroll
      for (int tt = 0; tt < 4; ++tt)
#pragma unroll
        for (int i = 0; i < 4; ++i) v = fmaxf(v, st[qs][tt][i]);
      v = fmaxf(v, __shfl_xor(v, 16));
      v = fmaxf(v, __shfl_xor(v, 32));
      vmax[qs] = v;
    }
    // ---- defer-max rescale ----
    const float grow = fmaxf(vmax[0] - m_[0], vmax[1] - m_[1]);
    if (!__all(grow <= 8.0f)) {
#pragma unroll
      for (int qs = 0; qs < 2; ++qs) {
        const float mn = fmaxf(m_[qs], vmax[qs]);
        const float cf = __expf(m_[qs] - mn);
        l_[qs] *= cf;
        m_[qs] = mn;
#pragma unroll
        for (int tt = 0; tt < 8; ++tt)
#pragma unroll
          for (int i = 0; i < 4; ++i) o[qs][tt][i] *= cf;
      }
    }
    // ---- exp, sum, pack P (slot-linear LDS: conflict-free pa reads) ----
#pragma unroll
    for (int qs = 0; qs < 2; ++qs) {
      float ps = 0.f;
#pragma unroll
      for (int tt = 0; tt < 4; ++tt) {
        const float e0 = __expf(st[qs][tt][0] - m_[qs]);
        const float e1 = __expf(st[qs][tt][1] - m_[qs]);
        const float e2 = __expf(st[qs][tt][2] - m_[qs]);
        const float e3 = __expf(st[qs][tt][3] - m_[qs]);
        ps += (e0 + e1) + (e2 + e3);
        uint2 pw;
        pw.x = (unsigned)f2b(e0) | ((unsigned)f2b(e1) << 16);
        pw.y = (unsigned)f2b(e2) | ((unsigned)f2b(e3) << 16);
        const int key = tt * 16 + rg;            // keys key..key+3
        *(uint2*)&Ps[w][qs * 1024 + (key >> 5) * 512 + r * 32 + ((key & 31) >> 3) * 8 + (key & 7)] = pw;
      }
      ps += __shfl_xor(ps, 16);
      ps += __shfl_xor(ps, 32);
      l_[qs] += ps;
    }

    // ---- PV: O(32q x 128d) += P(32x64) @ V(64x128) ----
    bf16x8 pa[2][2];
#pragma unroll
    for (int qs = 0; qs < 2; ++qs)
#pragma unroll
      for (int kb = 0; kb < 2; ++kb)
        pa[qs][kb] = *(const bf16x8*)&Ps[w][qs * 1024 + kb * 512 + r * 32 + hi * 8];
    __builtin_amdgcn_s_setprio(1);
#pragma unroll
    for (int tt = 0; tt < 8; ++tt) {
#pragma unroll
      for (int kb = 0; kb < 2; ++kb) {
        bf16x8 vf = *(const bf16x8*)(Vl + tt * 2048 + kb * 1024 + r * 64 + hi * 16);
#pragma unroll
        for (int qs = 0; qs < 2; ++qs)
          o[qs][tt] = __builtin_amdgcn_mfma_f32_16x16x32_bf16(pa[qs][kb], vf, o[qs][tt], 0, 0, 0);
      }
    }
    __builtin_amdgcn_s_setprio(0);

    __syncthreads();
    cur ^= 1;
  }

  // ---- epilogue: l_ lives at query=r lanes; o rows are query=rg+i -> shuffle ----
#pragma unroll
  for (int qs = 0; qs < 2; ++qs) {
    const float il = 1.f / l_[qs];
    float inv[4];
#pragma unroll
    for (int i = 0; i < 4; ++i)
      inv[i] = __shfl(il, (lane & 48) + rg + i);
    u16* op = attn_bf + (size_t)(b * LL + q0 + qs * 16 + rg) * DD + h * HDD;
#pragma unroll
    for (int tt = 0; tt < 8; ++tt)
#pragma unroll
      for (int i = 0; i < 4; ++i)
        op[(size_t)i * DD + tt * 16 + r] = f2b(o[qs][tt][i] * inv[i]);
  }
}

extern "C" void kernel_launch(void* const* d_in, const int* in_sizes, int n_in,
                              void* d_out, int out_size, void* d_ws, size_t ws_size,
                              hipStream_t stream) {
  const float* x    = (const float*)d_in[0];
  const float* cosb = (const float*)d_in[1];
  const float* sinb = (const float*)d_in[2];
  const float* Wq   = (const float*)d_in[3];
  const float* bq   = (const float*)d_in[4];
  const float* Wkv  = (const float*)d_in[5];
  const float* bkv  = (const float*)d_in[6];
  const float* Wrk  = (const float*)d_in[7];
  const float* brk  = (const float*)d_in[8];
  const float* Wo   = (const float*)d_in[9];
  const float* bo   = (const float*)d_in[10];
  float* out = (float*)d_out;

  char* ws = (char*)d_ws;
  float* kvbuf = (float*)(ws);
  float* krbuf = (float*)(ws + 8388608);
  float* qbuf  = (float*)(ws + 9437184);
  u16*   attn_bf = (u16*)(ws + 9437184);
  u16*   xb    = (u16*)(ws + 42991616);
  u16*   Qb    = (u16*)(ws + 42991616);
  u16*   Wob   = (u16*)(ws + 59768832);
  u16*   Wkvb  = (u16*)(ws + 68157440);
  u16*   Wrkb  = (u16*)(ws + 70254592);
  u16*   Wqb   = (u16*)(ws + 70516736);
  u16*   Kb    = (u16*)(ws + 70516736);
  u16*   VTb   = (u16*)(ws + 74711040);

  // 1) casts to bf16
  cast_bf16_kernel<<<(MM * DD / 4) / 256, 256, 0, stream>>>(x, xb, MM * DD / 4);
  cast_bf16_kernel<<<(HH * HDD * DD / 4) / 256, 256, 0, stream>>>(Wq, Wqb, HH * HDD * DD / 4);
  cast_bf16_kernel<<<(KVH * HDD * DD / 4) / 256, 256, 0, stream>>>(Wkv, Wkvb, KVH * HDD * DD / 4);
  cast_bf16_kernel<<<(RDD * DD / 4) / 256, 256, 0, stream>>>(Wrk, Wrkb, RDD * DD / 4);
  cast_bf16_kernel<<<(DD * HH * HDD / 4) / 256, 256, 0, stream>>>(Wo, Wob, DD * HH * HDD / 4);

  // 2) input projections (f32 out)
  gemm128<<<dim3(DD / 128, MM / 128), 256, 0, stream>>>(xb, Wqb, bq, qbuf, MM, DD, DD);
  gemm128<<<dim3((KVH * HDD) / 128, MM / 128), 256, 0, stream>>>(xb, Wkvb, bkv, kvbuf, MM, KVH * HDD, DD);
  gemm_bf16_nt<<<dim3(RDD / 16, MM / 16), 64, 0, stream>>>(xb, Wrkb, brk, krbuf, MM, RDD, DD);

  // 3) build bf16 attention operands (rope folded in)
  build_k_kernel<<<(BB * KVH * LL * HDD) / 256, 256, 0, stream>>>(kvbuf, krbuf, cosb, sinb, Kb);
  build_vt_kernel<<<dim3(LL / 32, HDD / 32, BB * KVH), 256, 0, stream>>>(kvbuf, VTb);
  build_q_kernel<<<(MM * HH * HDD) / 256, 256, 0, stream>>>(qbuf, cosb, sinb, Qb);

  // 4) MFMA flash attention v4 -> bf16
  attn_mfma4<<<dim3(512), 256, 0, stream>>>(Qb, Kb, VTb, attn_bf);

  // 5) output projection -> d_out (f32)
  gemm128<<<dim3(DD / 128, MM / 128), 256, 0, stream>>>(attn_bf, Wob, bo, out, MM, DD, DD);
}

// Round 8
// 328.226 us; speedup vs baseline: 1.0183x; 1.0183x over previous
//
#include <hip/hip_runtime.h>
#include <hip/hip_bf16.h>

// Problem constants
#define BB   2
#define LL   2048
#define DD   2048
#define HH   16
#define KVH  4
#define HDD  128
#define RDD  64
#define MM   (BB*LL)   // 4096 rows of x

typedef __attribute__((ext_vector_type(4))) float f32x4;
typedef __attribute__((ext_vector_type(8))) short bf16x8;
typedef unsigned short u16;

static __device__ __forceinline__ u16 f2b(float f) {
  __hip_bfloat16 b = __float2bfloat16(f);
  return *(const u16*)&b;
}

// async global(16B/lane) -> LDS (wave-uniform base + lane*16)
static __device__ __forceinline__ void gload_lds16(const void* g, void* l) {
  __builtin_amdgcn_global_load_lds(
      (const __attribute__((address_space(1))) unsigned int*)g,
      (__attribute__((address_space(3))) unsigned int*)l, 16, 0, 0);
}

// ---------------- f32 -> bf16 cast (vectorized) ----------------
__global__ __launch_bounds__(256) void cast_bf16_kernel(const float* __restrict__ in,
                                                        u16* __restrict__ out, int n4) {
  int i = blockIdx.x * 256 + threadIdx.x;
  if (i >= n4) return;
  float4 v = ((const float4*)in)[i];
  ushort4 o;
  o.x = f2b(v.x); o.y = f2b(v.y); o.z = f2b(v.z); o.w = f2b(v.w);
  ((ushort4*)out)[i] = o;
}

// ---------------- small GEMM (N=64): C[M,N] = A @ W^T + bias ----------------
__global__ __launch_bounds__(64) void gemm_bf16_nt(const u16* __restrict__ A,
                                                   const u16* __restrict__ W,
                                                   const float* __restrict__ bias,
                                                   float* __restrict__ C,
                                                   int M, int N, int K) {
  const int n0 = blockIdx.x * 16;
  const int m0 = blockIdx.y * 16;
  const int lane = threadIdx.x;
  const int r  = lane & 15;
  const int kq = (lane >> 4) * 8;
  const u16* ap = A + (size_t)(m0 + r) * K + kq;
  const u16* wp = W + (size_t)(n0 + r) * K + kq;
  f32x4 acc = {0.f, 0.f, 0.f, 0.f};
  for (int k = 0; k < K; k += 32) {
    bf16x8 a = *(const bf16x8*)(ap + k);
    bf16x8 b = *(const bf16x8*)(wp + k);
    acc = __builtin_amdgcn_mfma_f32_16x16x32_bf16(a, b, acc, 0, 0, 0);
  }
  const int col = lane & 15;
  const int rg  = (lane >> 4) * 4;
  const float bv = bias[n0 + col];
#pragma unroll
  for (int i = 0; i < 4; ++i)
    C[(size_t)(m0 + rg + i) * N + (n0 + col)] = acc[i] + bv;
}

// ---------------- m97-style 128x128 tile GEMM ----
__global__ __launch_bounds__(256) void gemm128(const u16* __restrict__ A,
                                               const u16* __restrict__ W,
                                               const float* __restrict__ bias,
                                               float* __restrict__ C,
                                               int M, int N, int K) {
  __shared__ u16 As[128 * 32];
  __shared__ u16 Bs[128 * 32];
  const int w = threadIdx.x >> 6, lane = threadIdx.x & 63;
  const int r = lane & 15, hi = lane >> 4, rg = hi * 4;
  const int wm = w >> 1, wn = w & 1;
  const int m0 = blockIdx.y * 128, n0 = blockIdx.x * 128;
  const int srow = w * 32 + (lane >> 2);
  const int scb  = (lane & 3) * 16;
  f32x4 acc[4][4];
#pragma unroll
  for (int i = 0; i < 4; ++i)
#pragma unroll
    for (int j = 0; j < 4; ++j) acc[i][j] = (f32x4){0.f, 0.f, 0.f, 0.f};

  for (int k0 = 0; k0 < K; k0 += 32) {
#pragma unroll
    for (int i = 0; i < 2; ++i) {
      gload_lds16((const char*)(A + (size_t)(m0 + srow + i * 16) * K + k0) + scb,
                  (char*)As + (w * 2 + i) * 1024);
      gload_lds16((const char*)(W + (size_t)(n0 + srow + i * 16) * K + k0) + scb,
                  (char*)Bs + (w * 2 + i) * 1024);
    }
    __syncthreads();
    bf16x8 a[4], b[4];
#pragma unroll
    for (int i = 0; i < 4; ++i)
      a[i] = *(const bf16x8*)((const char*)As + (wm * 64 + i * 16 + r) * 64 + hi * 16);
#pragma unroll
    for (int j = 0; j < 4; ++j)
      b[j] = *(const bf16x8*)((const char*)Bs + (wn * 64 + j * 16 + r) * 64 + hi * 16);
#pragma unroll
    for (int i = 0; i < 4; ++i)
#pragma unroll
      for (int j = 0; j < 4; ++j)
        acc[i][j] = __builtin_amdgcn_mfma_f32_16x16x32_bf16(a[i], b[j], acc[i][j], 0, 0, 0);
    __syncthreads();
  }
#pragma unroll
  for (int j = 0; j < 4; ++j) {
    const float bv = bias[n0 + wn * 64 + j * 16 + r];
#pragma unroll
    for (int i = 0; i < 4; ++i)
#pragma unroll
      for (int ii = 0; ii < 4; ++ii)
        C[(size_t)(m0 + wm * 64 + i * 16 + rg + ii) * N + n0 + wn * 64 + j * 16 + r] =
            acc[i][j][ii] + bv;
  }
}

// log2(e)/sqrt(128): scores land in exp2 domain
#define QSCALE 0.1275174313f

// ---------------- build Qb in fragment-granule order ----------------
// Per q-tile (16 q) image 4KB: off_u16 = qt*2048 + ks*512 + hi*128 + r*8
// granule: Q[qtile*16+r][ks*32+hi*8 .. +8] (rope + qscale folded)
__global__ __launch_bounds__(256) void build_q2(const float* __restrict__ qbuf,
                                                const float* __restrict__ cosb,
                                                const float* __restrict__ sinb,
                                                u16* __restrict__ Qb) {
  const int tid = blockIdx.x * 256 + threadIdx.x;   // granule id
  const int r  = tid & 15;
  const int hi = (tid >> 4) & 3;
  const int ks = (tid >> 6) & 3;
  const int qt = tid >> 8;                          // bh*128 + qtile
  const int qtile = qt & 127, bh = qt >> 7;
  const int h = bh & 15, b = bh >> 4;
  const int n = b * LL + qtile * 16 + r;
  const int d0 = ks * 32 + hi * 8;
  const float* qp = qbuf + (size_t)n * DD + h * HDD;
  float v[8];
  if (d0 < 64) {
#pragma unroll
    for (int j = 0; j < 8; ++j) v[j] = qp[d0 + j];
  } else {
    const int i0 = d0 - 64;
    const float* cb = cosb + (size_t)n * RDD + i0;
    const float* sb = sinb + (size_t)n * RDD + i0;
    if (i0 < 32) {
#pragma unroll
      for (int j = 0; j < 8; ++j) v[j] = qp[d0 + j] * cb[j] - qp[d0 + j + 32] * sb[j];
    } else {
#pragma unroll
      for (int j = 0; j < 8; ++j) v[j] = qp[d0 + j] * cb[j] + qp[d0 + j - 32] * sb[j];
    }
  }
  u16 o[8];
#pragma unroll
  for (int j = 0; j < 8; ++j) o[j] = f2b(v[j] * QSCALE);
  *(ushort4*)(Qb + (size_t)tid * 8)     = *(ushort4*)&o[0];
  *(ushort4*)(Qb + (size_t)tid * 8 + 4) = *(ushort4*)&o[4];
}

// ---------------- build Kb in tile-image order ----------------
// Per 64-key tile image 16KB: off_u16 = til*8192 + tt*2048 + ks*512 + hi*128 + r*8
// granule: K[stile*64+tt*16+r][ks*32+hi*8 .. +8], K = [kv_tied | roped k_rope]
__global__ __launch_bounds__(256) void build_k2(const float* __restrict__ kvbuf,
                                                const float* __restrict__ krbuf,
                                                const float* __restrict__ cosb,
                                                const float* __restrict__ sinb,
                                                u16* __restrict__ Kb) {
  const int tid = blockIdx.x * 256 + threadIdx.x;   // granule id
  const int r  = tid & 15;
  const int hi = (tid >> 4) & 3;
  const int ks = (tid >> 6) & 3;
  const int tt = (tid >> 8) & 3;
  const int til = tid >> 10;                        // bc*32 + stile
  const int stile = til & 31, bc = til >> 5;
  const int b = bc >> 2, c = bc & 3;
  const int s = stile * 64 + tt * 16 + r;
  const int n = b * LL + s;
  const int d0 = ks * 32 + hi * 8;
  float v[8];
  if (d0 < 64) {
    const float* kp = kvbuf + (size_t)n * (KVH * HDD) + c * HDD + d0;
#pragma unroll
    for (int j = 0; j < 8; ++j) v[j] = kp[j];
  } else {
    const int i0 = d0 - 64;
    const float* kr = krbuf + (size_t)n * RDD;
    const float* cb = cosb + (size_t)n * RDD + i0;
    const float* sb = sinb + (size_t)n * RDD + i0;
    if (i0 < 32) {
#pragma unroll
      for (int j = 0; j < 8; ++j) v[j] = kr[i0 + j] * cb[j] - kr[i0 + j + 32] * sb[j];
    } else {
#pragma unroll
      for (int j = 0; j < 8; ++j) v[j] = kr[i0 + j] * cb[j] + kr[i0 + j - 32] * sb[j];
    }
  }
  u16 o[8];
#pragma unroll
  for (int j = 0; j < 8; ++j) o[j] = f2b(v[j]);
  *(ushort4*)(Kb + (size_t)tid * 8)     = *(ushort4*)&o[0];
  *(ushort4*)(Kb + (size_t)tid * 8 + 4) = *(ushort4*)&o[4];
}

// ---------------- build VT in tile-image order (transpose via LDS) ----------------
// Per 64-key tile image 16KB: chunk j = tt*2+kb: j*512 + hi*128 + r*8;
// granule: VT[d=(j>>1)*16+r][s0+(j&1)*32+hi*8 .. +8]
__global__ __launch_bounds__(256) void build_v2(const float* __restrict__ kvbuf,
                                                u16* __restrict__ VT) {
  __shared__ float tile[64][132];
  const int til = blockIdx.x;                       // bc*32 + stile
  const int stile = til & 31, bc = til >> 5;
  const int b = bc >> 2, c = bc & 3;
  const int t = threadIdx.x;
  // load 64 x 128 f32 (coalesced)
#pragma unroll
  for (int it = 0; it < 8; ++it) {
    const int off = t * 4 + it * 1024;
    const int sl = off >> 7, d = off & 127;
    const float4 f = *(const float4*)(kvbuf + (size_t)(b * LL + stile * 64 + sl) * (KVH * HDD) + c * HDD + d);
    tile[sl][d] = f.x; tile[sl][d + 1] = f.y; tile[sl][d + 2] = f.z; tile[sl][d + 3] = f.w;
  }
  __syncthreads();
  // write granules (coalesced 16B stores)
#pragma unroll
  for (int it = 0; it < 4; ++it) {
    const int g = t + it * 256;                     // 0..1023
    const int r = g & 15, hi = (g >> 4) & 3, j = g >> 6;
    const int d = (j >> 1) * 16 + r;
    const int sl0 = (j & 1) * 32 + hi * 8;
    u16 o[8];
#pragma unroll
    for (int j2 = 0; j2 < 8; ++j2) o[j2] = f2b(tile[sl0 + j2][d]);
    u16* dst = VT + (size_t)til * 8192 + (size_t)g * 8;
    *(ushort4*)dst = *(ushort4*)&o[0];
    *(ushort4*)(dst + 4) = *(ushort4*)&o[4];
  }
}

// ---------------- stage one 64-key tile (K+V images, 16KB each) ----------------
static __device__ __forceinline__ void stage64(const u16* Kt, const u16* Vt,
                                               u16* kbuf, u16* vbuf,
                                               int w, int lane) {
#pragma unroll
  for (int i = 0; i < 4; ++i) {
    const int j = w * 4 + i;                        // slot 0..15
    gload_lds16(Kt + (size_t)j * 512 + lane * 8, kbuf + j * 512);
    gload_lds16(Vt + (size_t)j * 512 + lane * 8, vbuf + j * 512);
  }
}

// ---------------- MFMA flash attention v5: quarter-wave-clean LDS ----------------
// grid 512; 4 waves x 32 q; KVB=64 double-buffered; swapped QK^T; exp2-domain softmax.
__global__ __launch_bounds__(256, 1) void attn_mfma5(const u16* __restrict__ Qb,
                                                     const u16* __restrict__ Kb,
                                                     const u16* __restrict__ VTb,
                                                     u16* __restrict__ attn_bf) {
  const int id = blockIdx.x;
  const int bh = id & 31;
  const int strip = id >> 5;
  const int qb = (strip < 8) ? (15 - strip) : (strip - 8);
  const int b = bh >> 4, h = bh & 15, c = h >> 2;
  const int w = threadIdx.x >> 6, lane = threadIdx.x & 63;
  const int r = lane & 15, hi = lane >> 4, rg = hi * 4;
  const int q0 = qb * 128 + w * 32;

  __shared__ u16 Ks[2][8192];                       // 16KB x2
  __shared__ u16 Vs[2][8192];                       // 16KB x2
  __shared__ __align__(16) u16 Ps[4][2048];         // 4KB per wave

  const u16* Ktg = Kb + (size_t)(b * KVH + c) * 32 * 8192;   // per-(b,c) tile images
  const u16* Vtg = VTb + (size_t)(b * KVH + c) * 32 * 8192;

  // Q fragments (coalesced granule loads)
  bf16x8 qf[2][4];
#pragma unroll
  for (int qs = 0; qs < 2; ++qs) {
    const u16* qtb = Qb + (size_t)(bh * 128 + qb * 8 + w * 2 + qs) * 2048;
#pragma unroll
    for (int ks = 0; ks < 4; ++ks)
      qf[qs][ks] = *(const bf16x8*)(qtb + ks * 512 + lane * 8);
  }

  float m_[2] = {-3.0e38f, -3.0e38f}, l_[2] = {0.f, 0.f};
  f32x4 o[2][8];
#pragma unroll
  for (int qs = 0; qs < 2; ++qs)
#pragma unroll
    for (int t = 0; t < 8; ++t) o[qs][t] = (f32x4){0.f, 0.f, 0.f, 0.f};

  const int nt = 2 * qb + 2;                        // 64-key tiles (block-uniform)

  stage64(Ktg, Vtg, Ks[0], Vs[0], w, lane);
  __syncthreads();
  int cur = 0;

  for (int t = 0; t < nt; ++t) {
    const int s0 = t * 64;
    if (t + 1 < nt)
      stage64(Ktg + (size_t)(t + 1) * 8192, Vtg + (size_t)(t + 1) * 8192,
              Ks[cur ^ 1], Vs[cur ^ 1], w, lane);

    if (s0 <= q0 + 31) {                            // wave-uniform: skip fully-masked tiles
      const u16* Kl = Ks[cur];
      const u16* Vl = Vs[cur];

      // ---- swapped QK^T: st[qs][tt]: query col = r, key rows = tt*16 + rg + i ----
      f32x4 st[2][4];
#pragma unroll
      for (int qs = 0; qs < 2; ++qs)
#pragma unroll
        for (int tt = 0; tt < 4; ++tt) st[qs][tt] = (f32x4){0.f, 0.f, 0.f, 0.f};
      __builtin_amdgcn_s_setprio(1);
#pragma unroll
      for (int tt = 0; tt < 4; ++tt) {
        bf16x8 kf[4];
#pragma unroll
        for (int ks = 0; ks < 4; ++ks)
          kf[ks] = *(const bf16x8*)(Kl + tt * 2048 + ks * 512 + lane * 8);
#pragma unroll
        for (int qs = 0; qs < 2; ++qs)
#pragma unroll
          for (int ks = 0; ks < 4; ++ks)
            st[qs][tt] = __builtin_amdgcn_mfma_f32_16x16x32_bf16(kf[ks], qf[qs][ks], st[qs][tt], 0, 0, 0);
      }
      __builtin_amdgcn_s_setprio(0);

      // ---- causal mask ----
      if (s0 + 63 > q0) {
#pragma unroll
        for (int qs = 0; qs < 2; ++qs)
#pragma unroll
          for (int tt = 0; tt < 4; ++tt)
#pragma unroll
            for (int i = 0; i < 4; ++i)
              if (s0 + tt * 16 + rg + i > q0 + qs * 16 + r) st[qs][tt][i] = -3.0e38f;
      }

      // ---- in-lane max + 2 shuffles (exp2 domain) ----
      float vmax[2];
#pragma unroll
      for (int qs = 0; qs < 2; ++qs) {
        float v = st[qs][0][0];
#pragma unroll
        for (int tt = 0; tt < 4; ++tt)
#pragma unroll
          for (int i = 0; i < 4; ++i) v = fmaxf(v, st[qs][tt][i]);
        v = fmaxf(v, __shfl_xor(v, 16));
        v = fmaxf(v, __shfl_xor(v, 32));
        vmax[qs] = v;
      }
      // ---- defer-max rescale (thr 8 nats = 11.54 bits) ----
      const float grow = fmaxf(vmax[0] - m_[0], vmax[1] - m_[1]);
      if (!__all(grow <= 11.54f)) {
#pragma unroll
        for (int qs = 0; qs < 2; ++qs) {
          const float mn = fmaxf(m_[qs], vmax[qs]);
          const float cf = exp2f(m_[qs] - mn);
          l_[qs] *= cf;
          m_[qs] = mn;
#pragma unroll
          for (int tt = 0; tt < 8; ++tt)
#pragma unroll
            for (int i = 0; i < 4; ++i) o[qs][tt][i] *= cf;
        }
      }
      // ---- exp2, sum, pack P into granule layout ----
#pragma unroll
      for (int qs = 0; qs < 2; ++qs) {
        float ps = 0.f;
#pragma unroll
        for (int tt = 0; tt < 4; ++tt) {
          const float e0 = exp2f(st[qs][tt][0] - m_[qs]);
          const float e1 = exp2f(st[qs][tt][1] - m_[qs]);
          const float e2 = exp2f(st[qs][tt][2] - m_[qs]);
          const float e3 = exp2f(st[qs][tt][3] - m_[qs]);
          ps += (e0 + e1) + (e2 + e3);
          uint2 pw;
          pw.x = (unsigned)f2b(e0) | ((unsigned)f2b(e1) << 16);
          pw.y = (unsigned)f2b(e2) | ((unsigned)f2b(e3) << 16);
          const int k0 = tt * 16 + rg;              // keys k0..k0+3
          // granule layout: qs*1024 + (k0>>5)*512 + ((k0>>3)&3)*128 + r*8 + (k0&7)
          *(uint2*)&Ps[w][qs * 1024 + (k0 >> 5) * 512 + ((k0 >> 3) & 3) * 128 + r * 8 + (k0 & 7)] = pw;
        }
        ps += __shfl_xor(ps, 16);
        ps += __shfl_xor(ps, 32);
        l_[qs] += ps;
      }

      // ---- PV: O(32q x 128d) += P(32x64) @ V(64x128) ----
      bf16x8 pa[2][2];
#pragma unroll
      for (int qs = 0; qs < 2; ++qs)
#pragma unroll
        for (int kb = 0; kb < 2; ++kb)
          pa[qs][kb] = *(const bf16x8*)&Ps[w][qs * 1024 + kb * 512 + lane * 8];
      __builtin_amdgcn_s_setprio(1);
#pragma unroll
      for (int tt = 0; tt < 8; ++tt) {
#pragma unroll
        for (int kb = 0; kb < 2; ++kb) {
          bf16x8 vf = *(const bf16x8*)(Vl + tt * 1024 + kb * 512 + lane * 8);
#pragma unroll
          for (int qs = 0; qs < 2; ++qs)
            o[qs][tt] = __builtin_amdgcn_mfma_f32_16x16x32_bf16(pa[qs][kb], vf, o[qs][tt], 0, 0, 0);
        }
      }
      __builtin_amdgcn_s_setprio(0);
    }

    __syncthreads();
    cur ^= 1;
  }

  // ---- epilogue: l_ lives at query=r lanes; o rows are query=rg+i -> shuffle ----
#pragma unroll
  for (int qs = 0; qs < 2; ++qs) {
    const float il = 1.f / l_[qs];
    float inv[4];
#pragma unroll
    for (int i = 0; i < 4; ++i)
      inv[i] = __shfl(il, (lane & 48) + rg + i);
    u16* op = attn_bf + (size_t)(b * LL + q0 + qs * 16 + rg) * DD + h * HDD;
#pragma unroll
    for (int tt = 0; tt < 8; ++tt)
#pragma unroll
      for (int i = 0; i < 4; ++i)
        op[(size_t)i * DD + tt * 16 + r] = f2b(o[qs][tt][i] * inv[i]);
  }
}

extern "C" void kernel_launch(void* const* d_in, const int* in_sizes, int n_in,
                              void* d_out, int out_size, void* d_ws, size_t ws_size,
                              hipStream_t stream) {
  const float* x    = (const float*)d_in[0];
  const float* cosb = (const float*)d_in[1];
  const float* sinb = (const float*)d_in[2];
  const float* Wq   = (const float*)d_in[3];
  const float* bq   = (const float*)d_in[4];
  const float* Wkv  = (const float*)d_in[5];
  const float* bkv  = (const float*)d_in[6];
  const float* Wrk  = (const float*)d_in[7];
  const float* brk  = (const float*)d_in[8];
  const float* Wo   = (const float*)d_in[9];
  const float* bo   = (const float*)d_in[10];
  float* out = (float*)d_out;

  char* ws = (char*)d_ws;
  float* kvbuf = (float*)(ws);
  float* krbuf = (float*)(ws + 8388608);
  float* qbuf  = (float*)(ws + 9437184);
  u16*   attn_bf = (u16*)(ws + 9437184);
  u16*   xb    = (u16*)(ws + 42991616);
  u16*   Qb    = (u16*)(ws + 42991616);
  u16*   Wob   = (u16*)(ws + 59768832);
  u16*   Wkvb  = (u16*)(ws + 68157440);
  u16*   Wrkb  = (u16*)(ws + 70254592);
  u16*   Wqb   = (u16*)(ws + 70516736);
  u16*   Kb    = (u16*)(ws + 70516736);
  u16*   VTb   = (u16*)(ws + 74711040);

  // 1) casts to bf16
  cast_bf16_kernel<<<(MM * DD / 4) / 256, 256, 0, stream>>>(x, xb, MM * DD / 4);
  cast_bf16_kernel<<<(HH * HDD * DD / 4) / 256, 256, 0, stream>>>(Wq, Wqb, HH * HDD * DD / 4);
  cast_bf16_kernel<<<(KVH * HDD * DD / 4) / 256, 256, 0, stream>>>(Wkv, Wkvb, KVH * HDD * DD / 4);
  cast_bf16_kernel<<<(RDD * DD / 4) / 256, 256, 0, stream>>>(Wrk, Wrkb, RDD * DD / 4);
  cast_bf16_kernel<<<(DD * HH * HDD / 4) / 256, 256, 0, stream>>>(Wo, Wob, DD * HH * HDD / 4);

  // 2) input projections (f32 out)
  gemm128<<<dim3(DD / 128, MM / 128), 256, 0, stream>>>(xb, Wqb, bq, qbuf, MM, DD, DD);
  gemm128<<<dim3((KVH * HDD) / 128, MM / 128), 256, 0, stream>>>(xb, Wkvb, bkv, kvbuf, MM, KVH * HDD, DD);
  gemm_bf16_nt<<<dim3(RDD / 16, MM / 16), 64, 0, stream>>>(xb, Wrkb, brk, krbuf, MM, RDD, DD);

  // 3) build bf16 attention operands in fragment/tile-image layouts
  build_k2<<<(BB * KVH * LL * HDD / 8) / 256, 256, 0, stream>>>(kvbuf, krbuf, cosb, sinb, Kb);
  build_v2<<<BB * KVH * 32, 256, 0, stream>>>(kvbuf, VTb);
  build_q2<<<(MM * HH * HDD / 8) / 256, 256, 0, stream>>>(qbuf, cosb, sinb, Qb);

  // 4) MFMA flash attention v5 -> bf16
  attn_mfma5<<<dim3(512), 256, 0, stream>>>(Qb, Kb, VTb, attn_bf);

  // 5) output projection -> d_out (f32)
  gemm128<<<dim3(DD / 128, MM / 128), 256, 0, stream>>>(attn_bf, Wob, bo, out, MM, DD, DD);
}